// Round 15
// baseline (192.255 us; speedup 1.0000x reference)
//
#include <hip/hip_runtime.h>
#include <hip/hip_fp16.h>

// GCN 2-layer, N=100000, F=64, H=128, O=100, out [N,1] fp32.
// out = agg(relu(agg(x)@W1 + b1) . (W2@Wl)) + (b2@Wl + bl)
// agg via CSR-by-dst GATHER; layer-1 GEMV via MFMA (fp16 hi+lo split W1).
// PADDED CSR: bucket b owns [b*SCAP,(b+1)*SCAP); no counting pass.
// partA (merged with prep) multi-splits; partB counting-sorts in-bucket
// and emits rs/re + dinv + fp16 y. fused1 is fetch-bound (~2.5 TB/s random).

#define N_NODES 100000
#define F_IN 64
#define HID 128
#define OUT2 100
#define BSHIFT 8
#define BNODES 256
#define NBUCKETS ((N_NODES + BNODES - 1) / BNODES)  // 391
#define SCAP 4608   // bucket capacity: mean 4096 + 8 sigma (sigma=64)
#define ACHUNK 4096 // edges per partition block
#define NB_PAD 512
#define SENTB 0xFFFFu

typedef _Float16 half8 __attribute__((ext_vector_type(8)));
typedef float f32x4 __attribute__((ext_vector_type(4)));

static __device__ __forceinline__ half8 as_half8(uint4 u) {
    union { uint4 u; half8 h; } x; x.u = u; return x.h;
}

static __device__ __forceinline__ void accum8(float* f, uint4 u) {
    const __half2* hp = (const __half2*)&u;
    #pragma unroll
    for (int r = 0; r < 4; ++r) {
        float2 fv = __half22float2(hp[r]);
        f[2 * r] += fv.x; f[2 * r + 1] += fv.y;
    }
}

// Blocks 0..7: pack W1 (MFMA B-layout, fp16 hi+lo).
// Block 8: v = W2@Wl, c = b2.Wl + bl.
// Blocks 9..: LDS multi-split of edges into padded dst-buckets; ONE
// reserve-atomic per bucket per block (boff pre-zeroed by memset).
// Packed entry = (src<<8) | (dst&255).
__global__ __launch_bounds__(256) void partA_kernel(
    const float* __restrict__ W1, const float* __restrict__ W2,
    const float* __restrict__ b2, const float* __restrict__ Wl,
    const float* __restrict__ bl,
    float* __restrict__ v, float* __restrict__ c, uint4* __restrict__ Wpk,
    const int* __restrict__ src, const int* __restrict__ dst,
    int* __restrict__ boff, unsigned int* __restrict__ ebuf, int E) {
    int t = threadIdx.x;
    if (blockIdx.x < 8) {
        // idx: bit10 = part (0=hi,1=lo), bits9..7 = cb, bit6 = kf, bits5..0 = lane
        int idx = blockIdx.x * 256 + t;
        int lane2 = idx & 63;
        int kf    = (idx >> 6) & 1;
        int cb    = (idx >> 7) & 7;
        int part  = (idx >> 10) & 1;
        union { uint4 u; unsigned short s[8]; } pk;
        #pragma unroll
        for (int j = 0; j < 8; ++j) {
            int k    = kf * 32 + (lane2 >> 4) * 8 + j;
            int colg = cb * 16 + (lane2 & 15);
            float w = W1[k * HID + colg];
            __half h = __float2half_rn(w);
            if (part) h = __float2half_rn(w - __half2float(h));
            pk.s[j] = __half_as_ushort(h);
        }
        Wpk[idx] = pk.u;
        return;
    }
    if (blockIdx.x == 8) {
        if (t < HID) {
            float acc = 0.f;
            for (int k = 0; k < OUT2; ++k) acc += W2[t * OUT2 + k] * Wl[k];
            v[t] = acc;
        } else if (t == HID) {
            float acc = bl[0];
            for (int k = 0; k < OUT2; ++k) acc += b2[k] * Wl[k];
            *c = acc;
        }
        return;
    }
    __shared__ unsigned int stage[ACHUNK];       // 16 KB
    __shared__ unsigned short sb[ACHUNK];        // 8 KB
    __shared__ int hist[NB_PAD];
    __shared__ int ocnt[NB_PAD];
    __shared__ int gbase[NB_PAD];
    __shared__ int cnt2[NB_PAD];
    int chunk = blockIdx.x - 9;
    int base = chunk * ACHUNK;
    int total = E - base; if (total > ACHUNK) total = ACHUNK;

    hist[t] = 0; hist[t + 256] = 0;
    cnt2[t] = 0; cnt2[t + 256] = 0;
    __syncthreads();

    unsigned int pe[16];
    unsigned short bk[16];
    #pragma unroll
    for (int k = 0; k < 16; ++k) {
        int e = base + k * 256 + t;
        if (e < E) {
            int s = src[e], d = dst[e];
            pe[k] = ((unsigned int)s << 8) | (unsigned int)(d & (BNODES - 1));
            bk[k] = (unsigned short)(d >> BSHIFT);
            atomicAdd(&hist[bk[k]], 1);
        } else {
            bk[k] = SENTB;
        }
    }
    __syncthreads();
    ocnt[t] = hist[t]; ocnt[t + 256] = hist[t + 256];
    __syncthreads();
    for (int off = 1; off < NB_PAD; off <<= 1) {
        int v0 = (t >= off) ? hist[t - off] : 0;
        int v1 = hist[t + 256 - off];
        __syncthreads();
        hist[t] += v0; hist[t + 256] += v1;
        __syncthreads();
    }
    #pragma unroll
    for (int i = 0; i < 2; ++i) {
        int b = (t + i * 256 + chunk * 131) & (NB_PAD - 1);
        int cc = ocnt[b];
        if (cc > 0 && b < NBUCKETS)
            gbase[b] = b * SCAP + atomicAdd(&boff[b], cc);
    }
    __syncthreads();
    #pragma unroll
    for (int k = 0; k < 16; ++k) {
        if (bk[k] != SENTB) {
            int b = bk[k];
            int pos = (hist[b] - ocnt[b]) + atomicAdd(&cnt2[b], 1);
            stage[pos] = pe[k];
            sb[pos] = (unsigned short)b;
        }
    }
    __syncthreads();
    #pragma unroll
    for (int k = 0; k < 16; ++k) {
        int idx = k * 256 + t;
        if (idx < total) {
            int b = sb[idx];
            int lo = hist[b] - ocnt[b];
            ebuf[gbase[b] + (idx - lo)] = stage[idx];
        }
    }
}

// Pass B: one block per bucket, in-place counting sort in [b*SCAP, b*SCAP+cnt);
// emits per-node rs/re + dinv + fp16 pre-scaled y rows.
__global__ __launch_bounds__(256) void partB_kernel(
    const int* __restrict__ boff, unsigned int* __restrict__ csr,
    int* __restrict__ rs, int* __restrict__ re, float* __restrict__ dinv,
    const float4* __restrict__ x4, __half2* __restrict__ y2,
    int n, int do_y) {
    __shared__ int lcnt[BNODES];
    __shared__ int lscan[BNODES];
    __shared__ int lcur[BNODES];
    __shared__ float sdinv[BNODES];
    __shared__ unsigned int sbuf[SCAP];
    int b = blockIdx.x, t = threadIdx.x;
    int node0 = b << BSHIFT;
    int nlocal = min(BNODES, n - node0);
    int base = b * SCAP;
    int cnt = boff[b];
    lcnt[t] = 0;
    __syncthreads();
    unsigned int er[SCAP / 256];
    #pragma unroll
    for (int k = 0; k < SCAP / 256; ++k) {
        int idx = k * 256 + t;
        er[k] = (idx < cnt) ? csr[base + idx] : 0xFFFFFFFFu;
        if (er[k] != 0xFFFFFFFFu) atomicAdd(&lcnt[er[k] & (BNODES - 1)], 1);
    }
    __syncthreads();
    int own = lcnt[t];
    sdinv[t] = rsqrtf((float)own + 1.0f);
    lscan[t] = own;
    __syncthreads();
    for (int off = 1; off < BNODES; off <<= 1) {
        int v = (t >= off) ? lscan[t - off] : 0;
        __syncthreads();
        lscan[t] += v;
        __syncthreads();
    }
    int excl = lscan[t] - own;
    lcur[t] = excl;
    if (t < nlocal) {
        rs[node0 + t] = base + excl;
        re[node0 + t] = base + excl + own;
        dinv[node0 + t] = sdinv[t];
    }
    __syncthreads();
    #pragma unroll
    for (int k = 0; k < SCAP / 256; ++k) {
        unsigned int e = er[k];
        if (e != 0xFFFFFFFFu) {
            int p = atomicAdd(&lcur[(int)(e & (BNODES - 1))], 1);
            sbuf[p] = e >> 8;
        }
    }
    __syncthreads();
    for (int idx = t; idx < cnt; idx += 256) csr[base + idx] = sbuf[idx];
    if (do_y) {
        for (int i = t; i < nlocal * 16; i += 256) {
            int nl = i >> 4;
            int gi = (node0 + nl) * 16 + (i & 15);
            float di = sdinv[nl];
            float4 xv = x4[gi];
            y2[2 * gi]     = __floats2half2_rn(xv.x * di, xv.y * di);
            y2[2 * gi + 1] = __floats2half2_rn(xv.z * di, xv.w * di);
        }
    }
}

// Fused layer 1: block = 4 waves = 16 nodes (one MFMA tile).
// Gather phase interleaves the wave's 4 nodes (up to 8 y-gathers in flight).
__global__ __launch_bounds__(256) void fused1_kernel(
    const uint4* __restrict__ y, const float4* __restrict__ x4,
    const int* __restrict__ rs_, const int* __restrict__ re_,
    const int* __restrict__ csr,
    const float* __restrict__ dinv, const uint4* __restrict__ Wpk,
    const float* __restrict__ b1, const float* __restrict__ v,
    float* __restrict__ zz, int n) {
    __shared__ uint4 Atile[16 * 9];
    int t = threadIdx.x;
    int lane = t & 63;
    int wave = t >> 6;
    int node0 = blockIdx.x * 16;
    int q = lane >> 3, col = lane & 7;

    if (y) {
        int nodew = node0 + wave * 4;
        int rb[4], rend[4];
        #pragma unroll
        for (int m = 0; m < 4; ++m) { rb[m] = rs_[nodew + m]; rend[m] = re_[nodew + m]; }
        float f[4][8];
        #pragma unroll
        for (int m = 0; m < 4; ++m)
            #pragma unroll
            for (int r = 0; r < 8; ++r) f[m][r] = 0.f;
        if (q == 0) {
            #pragma unroll
            for (int m = 0; m < 4; ++m) {
                uint4 su = y[(nodew + m) * 8 + col];
                accum8(f[m], su);
            }
        }
        int pos[4], s0[4], s1[4];
        #pragma unroll
        for (int m = 0; m < 4; ++m) {
            pos[m] = rb[m];
            int p = pos[m] + q;
            s0[m] = (p < rend[m]) ? csr[p] : -1;
            s1[m] = (p + 8 < rend[m]) ? csr[p + 8] : -1;
        }
        while (true) {
            uint4 u0[4], u1[4];
            #pragma unroll
            for (int m = 0; m < 4; ++m) if (s0[m] >= 0) u0[m] = y[s0[m] * 8 + col];
            #pragma unroll
            for (int m = 0; m < 4; ++m) if (s1[m] >= 0) u1[m] = y[s1[m] * 8 + col];
            int n0[4], n1[4];
            #pragma unroll
            for (int m = 0; m < 4; ++m) {
                int np = pos[m] + 16 + q;
                n0[m] = (np < rend[m]) ? csr[np] : -1;
                n1[m] = (np + 8 < rend[m]) ? csr[np + 8] : -1;
            }
            #pragma unroll
            for (int m = 0; m < 4; ++m) {
                if (s0[m] >= 0) accum8(f[m], u0[m]);
                if (s1[m] >= 0) accum8(f[m], u1[m]);
            }
            bool more = false;
            #pragma unroll
            for (int m = 0; m < 4; ++m) {
                pos[m] += 16;
                more |= (pos[m] < rend[m]);
                s0[m] = n0[m]; s1[m] = n1[m];
            }
            if (!more) break;
        }
        #pragma unroll
        for (int m = 0; m < 4; ++m) {
            #pragma unroll
            for (int off = 8; off < 64; off <<= 1) {
                #pragma unroll
                for (int r = 0; r < 8; ++r) f[m][r] += __shfl_xor(f[m][r], off, 64);
            }
            if (lane < 8) {
                float di = dinv[nodew + m];
                union { uint4 u; __half2 h[4]; } pk;
                #pragma unroll
                for (int r = 0; r < 4; ++r)
                    pk.h[r] = __floats2half2_rn(di * f[m][2 * r], di * f[m][2 * r + 1]);
                Atile[(wave * 4 + m) * 9 + lane] = pk.u;
            }
        }
    } else {
        // f32 fallback: sequential per-node gather with per-src weight dinv[s]
        #pragma unroll
        for (int j = 0; j < 4; ++j) {
            int m = wave * 4 + j;
            int node = node0 + m;
            float f[8];
            #pragma unroll
            for (int r = 0; r < 8; ++r) f[r] = 0.f;
            int beg = rs_[node], end = re_[node];
            if (q == 0) {
                float di0 = dinv[node];
                float4 a = x4[node * 16 + 2 * col];
                float4 b = x4[node * 16 + 2 * col + 1];
                f[0] = di0 * a.x; f[1] = di0 * a.y; f[2] = di0 * a.z; f[3] = di0 * a.w;
                f[4] = di0 * b.x; f[5] = di0 * b.y; f[6] = di0 * b.z; f[7] = di0 * b.w;
            }
            int p = beg + q;
            int s0 = (p < end) ? csr[p] : -1;
            int s1 = (p + 8 < end) ? csr[p + 8] : -1;
            for (int cb = beg; cb < end; cb += 16) {
                int c0 = s0, c1 = s1;
                int np = cb + 16 + q;
                s0 = (np < end) ? csr[np] : -1;
                s1 = (np + 8 < end) ? csr[np + 8] : -1;
                if (c0 >= 0) {
                    float w = dinv[c0];
                    float4 a = x4[c0 * 16 + 2 * col];
                    float4 b = x4[c0 * 16 + 2 * col + 1];
                    f[0] += w * a.x; f[1] += w * a.y; f[2] += w * a.z; f[3] += w * a.w;
                    f[4] += w * b.x; f[5] += w * b.y; f[6] += w * b.z; f[7] += w * b.w;
                }
                if (c1 >= 0) {
                    float w = dinv[c1];
                    float4 a = x4[c1 * 16 + 2 * col];
                    float4 b = x4[c1 * 16 + 2 * col + 1];
                    f[0] += w * a.x; f[1] += w * a.y; f[2] += w * a.z; f[3] += w * a.w;
                    f[4] += w * b.x; f[5] += w * b.y; f[6] += w * b.z; f[7] += w * b.w;
                }
            }
            #pragma unroll
            for (int off = 8; off < 64; off <<= 1) {
                #pragma unroll
                for (int r = 0; r < 8; ++r) f[r] += __shfl_xor(f[r], off, 64);
            }
            if (lane < 8) {
                float di = dinv[node];
                union { uint4 u; __half2 h[4]; } pk;
                #pragma unroll
                for (int r = 0; r < 4; ++r)
                    pk.h[r] = __floats2half2_rn(di * f[2 * r], di * f[2 * r + 1]);
                Atile[m * 9 + lane] = pk.u;
            }
        }
    }
    __syncthreads();
    if (t >= 64) return;

    int mm = lane & 15, kq = lane >> 4;
    half8 A0 = as_half8(Atile[mm * 9 + kq]);
    half8 A1 = as_half8(Atile[mm * 9 + 4 + kq]);
    f32x4 acc[8];
    #pragma unroll
    for (int cb = 0; cb < 8; ++cb) acc[cb] = (f32x4){0.f, 0.f, 0.f, 0.f};
    #pragma unroll
    for (int cb = 0; cb < 8; ++cb) {
        half8 bh0 = as_half8(Wpk[(cb * 2 + 0) * 64 + lane]);
        half8 bh1 = as_half8(Wpk[(cb * 2 + 1) * 64 + lane]);
        half8 bl0 = as_half8(Wpk[1024 + (cb * 2 + 0) * 64 + lane]);
        half8 bl1 = as_half8(Wpk[1024 + (cb * 2 + 1) * 64 + lane]);
        acc[cb] = __builtin_amdgcn_mfma_f32_16x16x32_f16(A0, bh0, acc[cb], 0, 0, 0);
        acc[cb] = __builtin_amdgcn_mfma_f32_16x16x32_f16(A1, bh1, acc[cb], 0, 0, 0);
        acc[cb] = __builtin_amdgcn_mfma_f32_16x16x32_f16(A0, bl0, acc[cb], 0, 0, 0);
        acc[cb] = __builtin_amdgcn_mfma_f32_16x16x32_f16(A1, bl1, acc[cb], 0, 0, 0);
    }
    float zp[4] = {0.f, 0.f, 0.f, 0.f};
    #pragma unroll
    for (int cb = 0; cb < 8; ++cb) {
        int colg = cb * 16 + mm;
        float bb = b1[colg], vv = v[colg];
        #pragma unroll
        for (int r = 0; r < 4; ++r) {
            float h = acc[cb][r] + bb;
            h = fmaxf(h, 0.f);
            zp[r] += h * vv;
        }
    }
    #pragma unroll
    for (int off = 1; off < 16; off <<= 1) {
        #pragma unroll
        for (int r = 0; r < 4; ++r) zp[r] += __shfl_xor(zp[r], off, 64);
    }
    if (mm == 0) {
        int nb = node0 + kq * 4;
        #pragma unroll
        for (int r = 0; r < 4; ++r) zz[nb + r] = dinv[nb + r] * zp[r];
    }
}

// Layer 2 (collapsed): out[i] = c + dinv[i]*(zz[i] + sum_in zz[s]).
// 8 lanes/node, 4 pipelined slots per lane (csr prefetched a round ahead).
__global__ void out_kernel(const int* __restrict__ rs, const int* __restrict__ re,
                           const int* __restrict__ csr,
                           const float* __restrict__ dinv, const float* __restrict__ zz,
                           const float* __restrict__ c, float* __restrict__ out, int n) {
    int tid = blockIdx.x * blockDim.x + threadIdx.x;
    int node = tid >> 3;
    int sub = tid & 7;
    if (node >= n) return;
    int beg = rs[node], end = re[node];
    float acc = 0.f;
    int p = beg + sub;
    int s0 = (p < end) ? csr[p] : -1;
    int s1 = (p + 8 < end) ? csr[p + 8] : -1;
    int s2 = (p + 16 < end) ? csr[p + 16] : -1;
    int s3 = (p + 24 < end) ? csr[p + 24] : -1;
    for (int cb = beg; cb < end; cb += 32) {
        int c0 = s0, c1 = s1, c2 = s2, c3 = s3;
        int np = cb + 32 + sub;
        s0 = (np < end) ? csr[np] : -1;
        s1 = (np + 8 < end) ? csr[np + 8] : -1;
        s2 = (np + 16 < end) ? csr[np + 16] : -1;
        s3 = (np + 24 < end) ? csr[np + 24] : -1;
        float z0 = (c0 >= 0) ? zz[c0] : 0.f;
        float z1 = (c1 >= 0) ? zz[c1] : 0.f;
        float z2 = (c2 >= 0) ? zz[c2] : 0.f;
        float z3 = (c3 >= 0) ? zz[c3] : 0.f;
        acc += (z0 + z1) + (z2 + z3);
    }
    acc += __shfl_xor(acc, 1, 64);
    acc += __shfl_xor(acc, 2, 64);
    acc += __shfl_xor(acc, 4, 64);
    if (sub == 0) out[node] = c[0] + dinv[node] * (acc + zz[node]);
}

extern "C" void kernel_launch(void* const* d_in, const int* in_sizes, int n_in,
                              void* d_out, int out_size, void* d_ws, size_t ws_size,
                              hipStream_t stream) {
    const float* x  = (const float*)d_in[0];
    const int*   ei = (const int*)d_in[1];
    const float* W1 = (const float*)d_in[2];
    const float* b1 = (const float*)d_in[3];
    const float* W2 = (const float*)d_in[4];
    const float* b2 = (const float*)d_in[5];
    const float* Wl = (const float*)d_in[6];
    const float* bl = (const float*)d_in[7];
    float* out = (float*)d_out;

    int E = in_sizes[1] / 2;
    const int* src = ei;
    const int* dst = ei + E;

    float* ws      = (float*)d_ws;
    float* dinv    = ws;                        // N
    int*   rs      = (int*)(ws + N_NODES);      // N
    int*   re      = rs + N_NODES;              // N
    float* zz      = (float*)(re + N_NODES);    // N
    float* v       = zz + N_NODES;              // 128
    float* c       = v + HID;                   // 4
    int*   boff    = (int*)(c + 4);             // 512
    int*   csr     = boff + 512;                // NBUCKETS*SCAP
    uint4* Wpk     = (uint4*)(csr + (size_t)NBUCKETS * SCAP);  // 2048 uint4
    __half* y      = (__half*)((float*)Wpk + 8192);            // N*64 halves

    size_t base_floats = (size_t)N_NODES * 4 + 128 + 4 + 512
                       + (size_t)NBUCKETS * SCAP + 8192;
    size_t need_f16 = (base_floats + (size_t)N_NODES * 32) * 4;
    bool use_f16 = (ws_size >= need_f16);

    int nchunks = (E + ACHUNK - 1) / ACHUNK;   // 391

    hipMemsetAsync(boff, 0, sizeof(int) * 512, stream);
    partA_kernel<<<9 + nchunks, 256, 0, stream>>>(
        W1, W2, b2, Wl, bl, v, c, Wpk, src, dst, boff, (unsigned int*)csr, E);
    partB_kernel<<<NBUCKETS, 256, 0, stream>>>(
        boff, (unsigned int*)csr, rs, re, dinv,
        (const float4*)x, (__half2*)y, N_NODES, use_f16 ? 1 : 0);
    fused1_kernel<<<N_NODES / 16, 256, 0, stream>>>(
        use_f16 ? (const uint4*)y : nullptr, (const float4*)x,
        rs, re, csr, dinv, Wpk, b1, v, zz, N_NODES);
    out_kernel<<<(N_NODES * 8 + 255) / 256, 256, 0, stream>>>(
        rs, re, csr, dinv, zz, c, out, N_NODES);
}